// Round 5
// baseline (154.213 us; speedup 1.0000x reference)
//
#include <hip/hip_runtime.h>
#include <math.h>

typedef float    f4  __attribute__((ext_vector_type(4)));
typedef int      i4  __attribute__((ext_vector_type(4)));
typedef _Float16 hf8 __attribute__((ext_vector_type(8)));

namespace {

constexpr float kA0C0     = 0.8862269254527580f;  // pi / sqrt(4*pi)
constexpr float kA1C1     = 1.7724538509055159f;
constexpr float kA2C2     = 2.4270324670f;
constexpr float kAmbient  = 0.8f;
constexpr float kInvSigma = 1e4f;
constexpr float kInvGamma = 1e4f;
constexpr float kEps      = 1e-10f;
constexpr float kZfar     = 100.0f;
constexpr float kInvZrng  = 1.0f / 99.0f;   // 1/(ZFAR-ZNEAR)
constexpr float kExpCut   = -88.0f;         // exp underflow cutoff (f32)

// ---- Pass A: per-face SH shading -> split fp16 table, 20B/face = 4.0 MB ----
// tabA[f] = {v0.r,v0.g,v0.b, v1.r,v1.g,v1.b, v2.r,v2.g} fp16 (16B aligned)
// tabB[f] = v2.b as f32 (4B)
__global__ void shade_face_kernel(const float* __restrict__ vn,
                                  const float* __restrict__ vc,
                                  const float* __restrict__ sh,
                                  const int* __restrict__ faces,
                                  hf8* __restrict__ tabA,
                                  float* __restrict__ tabB, int F) {
  int f = blockIdx.x * blockDim.x + threadIdx.x;
  if (f >= F) return;
  float s0r = sh[0] + kAmbient, s0g = sh[1] + kAmbient, s0b = sh[2] + kAmbient;
  int vid[3] = {faces[3 * f + 0], faces[3 * f + 1], faces[3 * f + 2]};
  float col[9];
#pragma unroll
  for (int j = 0; j < 3; ++j) {
    int v = vid[j];
    float nx = vn[3 * v + 0], ny = vn[3 * v + 1], nz = vn[3 * v + 2];
    float nrm = fmaxf(sqrtf(nx * nx + ny * ny + nz * nz), 1e-6f);
    nx /= nrm; ny /= nrm; nz /= nrm;
    float Y1 = -kA1C1 * ny, Y2 = kA1C1 * nz, Y3 = -kA1C1 * nx;
    float Y4 =  kA2C2 * nx * ny, Y5 = -kA2C2 * ny * nz;
    float Y6 =  kA2C2 * (0.5f / 1.7320508075688772f) * (3.0f * nz * nz - 1.0f);
    float Y7 = -kA2C2 * nx * nz, Y8 = kA2C2 * 0.5f * (nx * nx - ny * ny);
    float r = kA0C0 * s0r + Y1 * sh[3] + Y2 * sh[6]  + Y3 * sh[9]  + Y4 * sh[12]
            + Y5 * sh[15] + Y6 * sh[18] + Y7 * sh[21] + Y8 * sh[24];
    float g = kA0C0 * s0g + Y1 * sh[4] + Y2 * sh[7]  + Y3 * sh[10] + Y4 * sh[13]
            + Y5 * sh[16] + Y6 * sh[19] + Y7 * sh[22] + Y8 * sh[25];
    float b = kA0C0 * s0b + Y1 * sh[5] + Y2 * sh[8]  + Y3 * sh[11] + Y4 * sh[14]
            + Y5 * sh[17] + Y6 * sh[20] + Y7 * sh[23] + Y8 * sh[26];
    col[3 * j + 0] = vc[3 * v + 0] * r;
    col[3 * j + 1] = vc[3 * v + 1] * g;
    col[3 * j + 2] = vc[3 * v + 2] * b;
  }
  hf8 a;
#pragma unroll
  for (int i = 0; i < 8; ++i) a[i] = (_Float16)col[i];
  tabA[f] = a;
  tabB[f] = col[8];
}

// ---- Pass B: softmax blend, 2 lanes per pixel (4 layers each), exact ----
__global__ void blend_kernel(const f4* __restrict__ bary4,
                             const f4* __restrict__ zb4,
                             const f4* __restrict__ ds4,
                             const i4* __restrict__ pf4,
                             const hf8* __restrict__ tabA,
                             const float* __restrict__ tabB,
                             f4* __restrict__ out, int T) {  // T = P*2
  int t = blockIdx.x * blockDim.x + threadIdx.x;
  if (t >= T) return;

  // Streaming loads (nontemporal: keep L2 for the gather table).
  i4 fv = __builtin_nontemporal_load(pf4 + t);
  f4 zv = __builtin_nontemporal_load(zb4 + t);
  f4 dv = __builtin_nontemporal_load(ds4 + t);
  f4 b0 = __builtin_nontemporal_load(bary4 + 3 * t);
  f4 b1 = __builtin_nontemporal_load(bary4 + 3 * t + 1);
  f4 b2 = __builtin_nontemporal_load(bary4 + 3 * t + 2);

  int   fk[4] = {fv.x, fv.y, fv.z, fv.w};
  float zz[4] = {zv.x, zv.y, zv.z, zv.w};
  float dd[4] = {dv.x, dv.y, dv.z, dv.w};
  float bw[12] = {b0.x, b0.y, b0.z, b0.w, b1.x, b1.y, b1.z, b1.w,
                  b2.x, b2.y, b2.z, b2.w};

  float pr[4], zi[4];
  float mx = 0.0f, om = 1.0f;
#pragma unroll
  for (int j = 0; j < 4; ++j) {
    bool m = fk[j] >= 0;
    float e = __expf(dd[j] * kInvSigma);
    float prv = m ? __builtin_amdgcn_rcpf(1.0f + e) : 0.0f;
    pr[j] = prv;
    om *= 1.0f - prv;
    float zva = m ? (kZfar - zz[j]) * kInvZrng : 0.0f;
    zi[j] = zva;
    mx = fmaxf(mx, zva);
  }

  // Pair reduction (lane t even/odd share pixel p = t>>1).
  float mxp = fmaxf(fmaxf(mx, __shfl_xor(mx, 1)), kEps);
  float alpha_om = om * __shfl_xor(om, 1);

  float delta = __expf((kEps - mxp) * kInvGamma);
  float den = 0.0f, cr = 0.0f, cg = 0.0f, cb = 0.0f;
#pragma unroll
  for (int j = 0; j < 4; ++j) {
    float edz = (zi[j] - mxp) * kInvGamma;
    float w = (edz > kExpCut) ? pr[j] * __expf(edz) : 0.0f;
    den += w;
    if (w != 0.0f) {                 // ~0.53 gathers per lane
      int f = fk[j];
      hf8  a  = tabA[f];             // L2-resident (4.0 MB table)
      float vb = tabB[f];
      float w0 = bw[3 * j + 0], w1 = bw[3 * j + 1], w2 = bw[3 * j + 2];
      cr += w * (w0 * (float)a[0] + w1 * (float)a[3] + w2 * (float)a[6]);
      cg += w * (w0 * (float)a[1] + w1 * (float)a[4] + w2 * (float)a[7]);
      cb += w * (w0 * (float)a[2] + w1 * (float)a[5] + w2 * vb);
    }
  }

  den += __shfl_xor(den, 1);
  cr  += __shfl_xor(cr, 1);
  cg  += __shfl_xor(cg, 1);
  cb  += __shfl_xor(cb, 1);

  if ((t & 1) == 0) {
    den += delta;
    float inv = __builtin_amdgcn_rcpf(den);
    f4 o;
    o.x = (cr + delta) * inv;        // BG = (1,1,1)
    o.y = (cg + delta) * inv;
    o.z = (cb + delta) * inv;
    o.w = 1.0f - alpha_om;
    __builtin_nontemporal_store(o, out + (t >> 1));
  }
}

}  // namespace

extern "C" void kernel_launch(void* const* d_in, const int* in_sizes, int n_in,
                              void* d_out, int out_size, void* d_ws, size_t ws_size,
                              hipStream_t stream) {
  const float* vn    = (const float*)d_in[0];
  const float* vc    = (const float*)d_in[1];
  const float* sh    = (const float*)d_in[2];
  const float* bary  = (const float*)d_in[3];
  const float* zbuf  = (const float*)d_in[4];
  const float* dists = (const float*)d_in[5];
  const int*   faces = (const int*)d_in[6];
  const int*   p2f   = (const int*)d_in[7];

  const int F = in_sizes[6] / 3;
  const int T = in_sizes[4] / 4;   // N*H*W*K/4 = P*2 threads

  hf8*   tabA = (hf8*)d_ws;                              // F*16B = 3.2 MB
  float* tabB = (float*)((char*)d_ws + ((size_t)F * 16 + 255 & ~(size_t)255));

  shade_face_kernel<<<(F + 255) / 256, 256, 0, stream>>>(vn, vc, sh, faces,
                                                         tabA, tabB, F);
  blend_kernel<<<(T + 255) / 256, 256, 0, stream>>>(
      (const f4*)bary, (const f4*)zbuf, (const f4*)dists, (const i4*)p2f,
      tabA, tabB, (f4*)d_out, T);
}

// Round 7
// 152.997 us; speedup vs baseline: 1.0079x; 1.0079x over previous
//
#include <hip/hip_runtime.h>
#include <math.h>

typedef float    f4  __attribute__((ext_vector_type(4)));
typedef int      i4  __attribute__((ext_vector_type(4)));
typedef _Float16 hf8 __attribute__((ext_vector_type(8)));

namespace {

constexpr float kA0C0     = 0.8862269254527580f;  // pi / sqrt(4*pi)
constexpr float kA1C1     = 1.7724538509055159f;
constexpr float kA2C2     = 2.4270324670f;
constexpr float kAmbient  = 0.8f;
constexpr float kInvSigma = 1e4f;
constexpr float kInvGamma = 1e4f;
constexpr float kEps      = 1e-10f;
constexpr float kZfar     = 100.0f;
constexpr float kInvZrng  = 1.0f / 99.0f;   // 1/(ZFAR-ZNEAR)
constexpr float kExpCut   = -88.0f;         // exp underflow cutoff (f32)
constexpr int   kBlendBlocks = 1024;        // 4 waves/SIMD resident

// ---- Pass A: per-face SH shading -> split fp16 table, 20B/face = 4.0 MB ----
// tabA[f] = {v0.r,v0.g,v0.b, v1.r,v1.g,v1.b, v2.r,v2.g} fp16; tabB[f] = v2.b f32
__global__ void shade_face_kernel(const float* __restrict__ vn,
                                  const float* __restrict__ vc,
                                  const float* __restrict__ sh,
                                  const int* __restrict__ faces,
                                  hf8* __restrict__ tabA,
                                  float* __restrict__ tabB, int F) {
  int f = blockIdx.x * blockDim.x + threadIdx.x;
  if (f >= F) return;
  float s0r = sh[0] + kAmbient, s0g = sh[1] + kAmbient, s0b = sh[2] + kAmbient;
  int vid[3] = {faces[3 * f + 0], faces[3 * f + 1], faces[3 * f + 2]};
  float col[9];
#pragma unroll
  for (int j = 0; j < 3; ++j) {
    int v = vid[j];
    float nx = vn[3 * v + 0], ny = vn[3 * v + 1], nz = vn[3 * v + 2];
    float nrm = fmaxf(sqrtf(nx * nx + ny * ny + nz * nz), 1e-6f);
    nx /= nrm; ny /= nrm; nz /= nrm;
    float Y1 = -kA1C1 * ny, Y2 = kA1C1 * nz, Y3 = -kA1C1 * nx;
    float Y4 =  kA2C2 * nx * ny, Y5 = -kA2C2 * ny * nz;
    float Y6 =  kA2C2 * (0.5f / 1.7320508075688772f) * (3.0f * nz * nz - 1.0f);
    float Y7 = -kA2C2 * nx * nz, Y8 = kA2C2 * 0.5f * (nx * nx - ny * ny);
    float r = kA0C0 * s0r + Y1 * sh[3] + Y2 * sh[6]  + Y3 * sh[9]  + Y4 * sh[12]
            + Y5 * sh[15] + Y6 * sh[18] + Y7 * sh[21] + Y8 * sh[24];
    float g = kA0C0 * s0g + Y1 * sh[4] + Y2 * sh[7]  + Y3 * sh[10] + Y4 * sh[13]
            + Y5 * sh[16] + Y6 * sh[19] + Y7 * sh[22] + Y8 * sh[25];
    float b = kA0C0 * s0b + Y1 * sh[5] + Y2 * sh[8]  + Y3 * sh[11] + Y4 * sh[14]
            + Y5 * sh[17] + Y6 * sh[20] + Y7 * sh[23] + Y8 * sh[26];
    col[3 * j + 0] = vc[3 * v + 0] * r;
    col[3 * j + 1] = vc[3 * v + 1] * g;
    col[3 * j + 2] = vc[3 * v + 2] * b;
  }
  hf8 a;
#pragma unroll
  for (int i = 0; i < 8; ++i) a[i] = (_Float16)col[i];
  tabA[f] = a;
  tabB[f] = col[8];
}

struct Px { i4 f0, f1; f4 z0, z1, d0, d1; };

__device__ __forceinline__ Px load_px(const i4* __restrict__ pf4,
                                      const f4* __restrict__ zb4,
                                      const f4* __restrict__ ds4, int p) {
  Px s;
  s.f0 = __builtin_nontemporal_load(pf4 + 2 * p);
  s.f1 = __builtin_nontemporal_load(pf4 + 2 * p + 1);
  s.z0 = __builtin_nontemporal_load(zb4 + 2 * p);
  s.z1 = __builtin_nontemporal_load(zb4 + 2 * p + 1);
  s.d0 = __builtin_nontemporal_load(ds4 + 2 * p);
  s.d1 = __builtin_nontemporal_load(ds4 + 2 * p + 1);
  return s;
}

__device__ __forceinline__ void process_px(
    int p, const Px& s,
    const float* __restrict__ bary,
    const hf8* __restrict__ tabA,
    const float* __restrict__ tabB,
    f4* __restrict__ out) {
  int   fk[8] = {s.f0.x, s.f0.y, s.f0.z, s.f0.w, s.f1.x, s.f1.y, s.f1.z, s.f1.w};
  float zz[8] = {s.z0.x, s.z0.y, s.z0.z, s.z0.w, s.z1.x, s.z1.y, s.z1.z, s.z1.w};
  float dd[8] = {s.d0.x, s.d0.y, s.d0.z, s.d0.w, s.d1.x, s.d1.y, s.d1.z, s.d1.w};

  float pr[8], zi[8];
  float maxz = kEps, alpha = 1.0f;
#pragma unroll
  for (int k = 0; k < 8; ++k) {
    bool m = fk[k] >= 0;
    float e = __expf(dd[k] * kInvSigma);
    float prv = m ? __builtin_amdgcn_rcpf(1.0f + e) : 0.0f;
    pr[k] = prv;
    alpha *= 1.0f - prv;
    float zv = m ? (kZfar - zz[k]) * kInvZrng : 0.0f;
    zi[k] = zv;
    maxz = fmaxf(maxz, zv);
  }

  float delta = __expf((kEps - maxz) * kInvGamma);
  float denom = delta;
  float cr = 0.0f, cg = 0.0f, cb = 0.0f;
#pragma unroll
  for (int k = 0; k < 8; ++k) {
    float edz = (zi[k] - maxz) * kInvGamma;
    float w = (edz > kExpCut) ? pr[k] * __expf(edz) : 0.0f;
    denom += w;
    if (w != 0.0f) {                  // ~1.06 of 8 layers per pixel
      int t = 8 * p + k;
      float b0 = bary[3 * t + 0], b1 = bary[3 * t + 1], b2 = bary[3 * t + 2];
      hf8  a  = tabA[fk[k]];          // 16B + 4B from warm table
      float vb = tabB[fk[k]];
      cr += w * (b0 * (float)a[0] + b1 * (float)a[3] + b2 * (float)a[6]);
      cg += w * (b0 * (float)a[1] + b1 * (float)a[4] + b2 * (float)a[7]);
      cb += w * (b0 * (float)a[2] + b1 * (float)a[5] + b2 * vb);
    }
  }

  float inv = __builtin_amdgcn_rcpf(denom);
  f4 o;
  o.x = (cr + delta) * inv;           // BG = (1,1,1)
  o.y = (cg + delta) * inv;
  o.z = (cb + delta) * inv;
  o.w = 1.0f - alpha;
  __builtin_nontemporal_store(o, out + p);
}

// ---- Pass B: grid-stride, 2-stage software pipeline (next loads before
// current compute) — long-lived waves keep the HBM pipe continuously fed. ----
__global__ void __launch_bounds__(256, 4) blend_kernel(
    const float* __restrict__ bary,
    const f4* __restrict__ zb4,
    const f4* __restrict__ ds4,
    const i4* __restrict__ pf4,
    const hf8* __restrict__ tabA,
    const float* __restrict__ tabB,
    f4* __restrict__ out, int P) {
  int tid = blockIdx.x * blockDim.x + threadIdx.x;
  int stride = gridDim.x * blockDim.x;
  if (tid >= P) return;

  int p = tid;
  Px cur = load_px(pf4, zb4, ds4, p);
  while (true) {
    int pn = p + stride;
    bool more = pn < P;
    Px nxt;
    if (more) nxt = load_px(pf4, zb4, ds4, pn);   // issue before compute
    process_px(p, cur, bary, tabA, tabB, out);
    if (!more) break;
    p = pn;
    cur = nxt;
  }
}

}  // namespace

extern "C" void kernel_launch(void* const* d_in, const int* in_sizes, int n_in,
                              void* d_out, int out_size, void* d_ws, size_t ws_size,
                              hipStream_t stream) {
  const float* vn    = (const float*)d_in[0];
  const float* vc    = (const float*)d_in[1];
  const float* sh    = (const float*)d_in[2];
  const float* bary  = (const float*)d_in[3];
  const float* zbuf  = (const float*)d_in[4];
  const float* dists = (const float*)d_in[5];
  const int*   faces = (const int*)d_in[6];
  const int*   p2f   = (const int*)d_in[7];

  const int F = in_sizes[6] / 3;
  const int P = in_sizes[4] / 8;   // N*H*W pixels (K = 8)

  hf8*   tabA = (hf8*)d_ws;                              // F*16B = 3.2 MB
  float* tabB = (float*)((char*)d_ws + (((size_t)F * 16 + 255) & ~(size_t)255));

  shade_face_kernel<<<(F + 255) / 256, 256, 0, stream>>>(vn, vc, sh, faces,
                                                         tabA, tabB, F);
  blend_kernel<<<kBlendBlocks, 256, 0, stream>>>(
      bary, (const f4*)zbuf, (const f4*)dists, (const i4*)p2f,
      tabA, tabB, (f4*)d_out, P);
}